// Round 8
// baseline (238.358 us; speedup 1.0000x reference)
//
#include <hip/hip_runtime.h>
#include <math.h>

// Cone-beam forward projection (TIGRE Ax analogue).
// Volume: [B=2, NZ=96, NY=96, NX=96] f32, ZYX layout (x fastest).
// Output: [B=2, A=48, NV=96, NU=96] f32.
//
// R8: ANGLE-ADAPTIVE DUAL LAYOUT. Two batch-interleaved float2 copies of the
// volume in d_ws: Qx[z][y][x] (x-fastest) and Qy[z][x][y] (y-fastest),
// 14.2 MB total. A wave's 64 consecutive-u rays spread ~51 voxels along
// u_ax=(-sin t, cos t); TA cost = distinct 64B lines per gather ~ 51*|perp
// component|. Picking the layout whose fast axis matches the spread cuts
// avg lines/inst from ~35 to ~23 (E|cos| = 0.64 -> E[min] = 0.373).
// Angle (hence layout) is uniform per block -> scalar branch, no divergence.
// Corner VALUES and lerp op-order identical to R7 -> bit-identical output.
//
// CORRECTNESS-CRITICAL: reference integrand is DISCONTINUOUS at cube faces.
// Position path replicates the reference's f32 op sequence exactly:
// contract(off), per-sample src + d*t, IEEE sqrt+div, f64-rounded trig.

#define NZg 96
#define NYg 96
#define NXg 96
#define NVg 96
#define NUg 96
#define NAg 48
#define NSg 96
#define NBg 2
#define NVOX (NZg * NYg * NXg)          // 884736 voxels per batch
#define NRAY1 (NAg * NVg * NUg)         // 442368 rays per batch
#define PLANE (NYg * NXg)               // 9216

// ---------------- staging: both layouts, batch-interleaved ----------------
__global__ __launch_bounds__(256) void pack_dual(
    const float* __restrict__ vol, float2* __restrict__ qx,
    float2* __restrict__ qy) {
    const int i = blockIdx.x * blockDim.x + threadIdx.x;  // [z][y][x]
    const int x = i % NXg;
    int t = i / NXg;
    const int y = t % NYg;
    const int z = t / NYg;
    float2 p;
    p.x = vol[i];
    p.y = vol[i + NVOX];
    qx[i] = p;                               // x-fastest (coalesced)
    qy[(z * NXg + x) * NYg + y] = p;         // y-fastest (transposed)
}

// ---------------- shared geometry (b-independent) -------------------------
__device__ __forceinline__ void ray_setup(
    int ridx, float& srcx, float& srcy, float& dx, float& dy, float& dz,
    float& cth, float& sth, int& k0, int& k1) {
#pragma clang fp contract(off)
    const int u   = ridx % NUg;
    int tmp       = ridx / NUg;
    const int v   = tmp % NVg;
    const int a   = tmp / NVg;          // < 48, uniform per block

    // theta = a * (f32(2*pi) / 48)   [jax linspace f32 semantics]
    const float dtheta = 6.2831855f / 48.0f;
    const float theta  = (float)a * dtheta;
    const float c = (float)cos((double)theta);
    const float s = (float)sin((double)theta);
    cth = c; sth = s;

    srcx = 500.0f * c;
    srcy = 500.0f * s;
    const float uu = ((float)u - 47.5f) * 2.0f;
    const float vv = ((float)v - 47.5f) * 2.0f;
    const float pixx = (-500.0f * c) + uu * (-s);
    const float pixy = (-500.0f * s) + uu * c;
    const float pixz = vv;

    const float dx0 = pixx - srcx;
    const float dy0 = pixy - srcy;
    const float dz0 = pixz;
    const float nrm = sqrtf((dx0 * dx0 + dy0 * dy0) + dz0 * dz0);
    dx = dx0 / nrm;
    dy = dy0 / nrm;
    dz = dz0 / nrm;

    const float stepf = (float)1.7320508075688773;   // f32(2R/96)
    const float t0f   = (float)416.8615612366939;    // f32(DSO-R)

    // conservative AABB clip (skip-only; in-loop test is authoritative)
    const float LO = -47.51f, HI = 47.51f;
    float tlo = -1e30f, thi = 1e30f;
    {
        const float o3[3] = {srcx, srcy, 0.0f};
        const float d3[3] = {dx, dy, dz};
        bool empty = false;
        #pragma unroll
        for (int ax = 0; ax < 3; ++ax) {
            const float oo = o3[ax], dd = d3[ax];
            if (fabsf(dd) > 1e-8f) {
                const float inv = 1.0f / dd;
                const float ta = (LO - oo) * inv;
                const float tb = (HI - oo) * inv;
                tlo = fmaxf(tlo, fminf(ta, tb));
                thi = fminf(thi, fmaxf(ta, tb));
            } else if (oo < LO || oo > HI) {
                empty = true;
            }
        }
        if (empty) { tlo = 1.0f; thi = 0.0f; }
    }
    if (thi >= tlo) {
        k0 = (int)floorf((tlo - t0f) / stepf) - 2;
        k1 = (int)ceilf((thi - t0f) / stepf) + 2;
        k0 = max(k0, 0);
        k1 = min(k1, NSg - 1);
    } else {
        k0 = 1; k1 = 0;
    }
}

// ---------------- main: both batches per thread, dual layout --------------
__global__ __launch_bounds__(256) void coneproj_dual(
    const float2* __restrict__ qx, const float2* __restrict__ qy,
    float* __restrict__ out) {
#pragma clang fp contract(off)
    const int ridx = blockIdx.x * blockDim.x + threadIdx.x;  // (a*96+v)*96+u
    float srcx, srcy, dx, dy, dz, cth, sth;
    int k0, k1;
    ray_setup(ridx, srcx, srcy, dx, dy, dz, cth, sth, k0, k1);

    const float stepf = (float)1.7320508075688773;
    const float t0f   = (float)416.8615612366939;

    // u-spread direction u_ax = (-s, c). Lines run along the layout's fast
    // axis; choose layout so the dominant spread is along that axis.
    // |s| >= |c| -> spread mostly x -> x-fast; else y-fast. Uniform per block.
    const bool use_y = fabsf(cth) > fabsf(sth);
    const float2* __restrict__ Q = use_y ? qy : qx;
    const int sX = use_y ? NYg : 1;     // element step for x+1
    const int sY = use_y ? 1 : NXg;     // element step for y+1

    float acc0 = 0.0f, acc1 = 0.0f;
    for (int k = k0; k <= k1; ++k) {
        const float tk = t0f + ((float)k + 0.5f) * stepf;
        const float ix = (srcx + dx * tk) + 47.5f;
        const float iy = (srcy + dy * tk) + 47.5f;
        const float iz = (dz * tk) + 47.5f;
        if (ix >= 0.0f && ix <= 95.0f &&
            iy >= 0.0f && iy <= 95.0f &&
            iz >= 0.0f && iz <= 95.0f) {
            const int x0 = min((int)ix, NXg - 2);
            const int y0 = min((int)iy, NYg - 2);
            const int z0 = min((int)iz, NZg - 2);
            const float fx = ix - (float)x0;
            const float fy = iy - (float)y0;
            const float fz = iz - (float)z0;
            const int inner = use_y ? (x0 * NYg + y0) : (y0 * NXg + x0);
            const int base  = z0 * PLANE + inner;
            // 8 aligned dwordx2 gathers; each carries BOTH batches' value
            const float2 q000 = Q[base];
            const float2 q001 = Q[base + sX];
            const float2 q010 = Q[base + sY];
            const float2 q011 = Q[base + sX + sY];
            const float2 q100 = Q[base + PLANE];
            const float2 q101 = Q[base + PLANE + sX];
            const float2 q110 = Q[base + PLANE + sY];
            const float2 q111 = Q[base + PLANE + sX + sY];
            // batch 0 (op-order identical to R2/R7)
            {
                const float c00 = q000.x + fx * (q001.x - q000.x);
                const float c01 = q010.x + fx * (q011.x - q010.x);
                const float c10 = q100.x + fx * (q101.x - q100.x);
                const float c11 = q110.x + fx * (q111.x - q110.x);
                const float c0  = c00 + fy * (c01 - c00);
                const float c1  = c10 + fy * (c11 - c10);
                acc0 += c0 + fz * (c1 - c0);
            }
            // batch 1
            {
                const float c00 = q000.y + fx * (q001.y - q000.y);
                const float c01 = q010.y + fx * (q011.y - q010.y);
                const float c10 = q100.y + fx * (q101.y - q100.y);
                const float c11 = q110.y + fx * (q111.y - q110.y);
                const float c0  = c00 + fy * (c01 - c00);
                const float c1  = c10 + fy * (c11 - c10);
                acc1 += c0 + fz * (c1 - c0);
            }
        }
    }
    out[ridx]         = acc0 * stepf;
    out[ridx + NRAY1] = acc1 * stepf;
}

// ---------------- fallback: direct 8-gather projector (R2) ----------------
__global__ __launch_bounds__(256) void coneproj_direct(
    const float* __restrict__ vol, float* __restrict__ out) {
#pragma clang fp contract(off)
    const int gidx = blockIdx.x * blockDim.x + threadIdx.x;  // includes b
    const int ridx = gidx % NRAY1;
    const int b    = gidx / NRAY1;
    float srcx, srcy, dx, dy, dz, cth, sth;
    int k0, k1;
    ray_setup(ridx, srcx, srcy, dx, dy, dz, cth, sth, k0, k1);

    const float stepf = (float)1.7320508075688773;
    const float t0f   = (float)416.8615612366939;

    const float* __restrict__ volb = vol + (size_t)b * NVOX;

    float acc = 0.0f;
    for (int k = k0; k <= k1; ++k) {
        const float tk = t0f + ((float)k + 0.5f) * stepf;
        const float ix = (srcx + dx * tk) + 47.5f;
        const float iy = (srcy + dy * tk) + 47.5f;
        const float iz = (dz * tk) + 47.5f;
        if (ix >= 0.0f && ix <= 95.0f &&
            iy >= 0.0f && iy <= 95.0f &&
            iz >= 0.0f && iz <= 95.0f) {
            const int x0 = min((int)ix, NXg - 2);
            const int y0 = min((int)iy, NYg - 2);
            const int z0 = min((int)iz, NZg - 2);
            const float fx = ix - (float)x0;
            const float fy = iy - (float)y0;
            const float fz = iz - (float)z0;
            const float* p = volb + ((z0 * NYg + y0) * NXg + x0);
            const float v000 = p[0];
            const float v001 = p[1];
            const float v010 = p[NXg];
            const float v011 = p[NXg + 1];
            const float v100 = p[NYg * NXg];
            const float v101 = p[NYg * NXg + 1];
            const float v110 = p[NYg * NXg + NXg];
            const float v111 = p[NYg * NXg + NXg + 1];
            const float c00 = v000 + fx * (v001 - v000);
            const float c01 = v010 + fx * (v011 - v010);
            const float c10 = v100 + fx * (v101 - v100);
            const float c11 = v110 + fx * (v111 - v110);
            const float c0  = c00 + fy * (c01 - c00);
            const float c1  = c10 + fy * (c11 - c10);
            acc += c0 + fz * (c1 - c0);
        }
    }
    out[gidx] = acc * stepf;
}

extern "C" void kernel_launch(void* const* d_in, const int* in_sizes, int n_in,
                              void* d_out, int out_size, void* d_ws, size_t ws_size,
                              hipStream_t stream) {
    const float* vol = (const float*)d_in[0];
    float* out = (float*)d_out;
    const size_t one = (size_t)NVOX * sizeof(float2);  // ~7.08 MB
    if (ws_size >= 2 * one) {
        float2* qx = (float2*)d_ws;
        float2* qy = qx + NVOX;
        pack_dual<<<NVOX / 256, 256, 0, stream>>>(vol, qx, qy);
        coneproj_dual<<<NRAY1 / 256, 256, 0, stream>>>(qx, qy, out);
    } else {
        coneproj_direct<<<(NBg * NRAY1) / 256, 256, 0, stream>>>(vol, out);
    }
}

// Round 9
// 220.608 us; speedup vs baseline: 1.0805x; 1.0805x over previous
//
#include <hip/hip_runtime.h>
#include <math.h>

// Cone-beam forward projection (TIGRE Ax analogue).
// Volume: [B=2, NZ=96, NY=96, NX=96] f32, ZYX layout (x fastest).
// Output: [B=2, A=48, NV=96, NU=96] f32.
//
// R9: TILED (4x × 2y) SINGLE LAYOUT, batch-interleaved float2, 7.1 MB.
// One 64B line = 8 float2 = a 4x*2y voxel tile (both batches). A wave's 64
// consecutive-u rays spread (64|s|,64|c|) voxels in (x,y); distinct lines
// per gather ~ 16|s|+32|c| vs R7's 8|s|+64|c| (x-fast rows): avg 0.67x,
// worst angle 0.5x. Footprint unchanged vs R7 -> no R8-style L2 thrash
// (R8: dual layout, FETCH 26->81 MB, regressed). Addressing keeps R7's
// base+delta form: dX=(x0&3)<3?1:5, dY=(y0&1)?188:4, dZ=9216.
// Corner VALUES and lerp op-order identical to R7 -> bit-identical output.
//
// CORRECTNESS-CRITICAL: reference integrand is DISCONTINUOUS at cube faces.
// Position path replicates the reference's f32 op sequence exactly:
// contract(off), per-sample src + d*t, IEEE sqrt+div, f64-rounded trig.

#define NZg 96
#define NYg 96
#define NXg 96
#define NVg 96
#define NUg 96
#define NAg 48
#define NSg 96
#define NBg 2
#define NVOX (NZg * NYg * NXg)          // 884736 voxels per batch
#define NRAY1 (NAg * NVg * NUg)         // 442368 rays per batch
#define PLANE (NYg * NXg)               // 9216 elements per z-plane
#define TROW  (24 * 8)                  // 192: elements per 2-y tile row

// tiled element index: z*9216 + (y>>1)*192 + (x>>2)*8 + (y&1)*4 + (x&3)
__device__ __forceinline__ int tiled_idx(int x, int y, int z) {
    return z * PLANE + (y >> 1) * TROW + (x >> 2) * 8 + (y & 1) * 4 + (x & 3);
}

// ---------------- staging: batch-interleave + tile ------------------------
__global__ __launch_bounds__(256) void pack_tiled(
    const float* __restrict__ vol, float2* __restrict__ q) {
    const int i = blockIdx.x * blockDim.x + threadIdx.x;  // [z][y][x] linear
    const int x = i % NXg;
    int t = i / NXg;
    const int y = t % NYg;
    const int z = t / NYg;
    float2 p;
    p.x = vol[i];
    p.y = vol[i + NVOX];
    q[tiled_idx(x, y, z)] = p;
}

// ---------------- shared geometry (b-independent) -------------------------
__device__ __forceinline__ void ray_setup(
    int ridx, float& srcx, float& srcy, float& dx, float& dy, float& dz,
    int& k0, int& k1) {
#pragma clang fp contract(off)
    const int u   = ridx % NUg;
    int tmp       = ridx / NUg;
    const int v   = tmp % NVg;
    const int a   = tmp / NVg;          // < 48, uniform per block

    // theta = a * (f32(2*pi) / 48)   [jax linspace f32 semantics]
    const float dtheta = 6.2831855f / 48.0f;
    const float theta  = (float)a * dtheta;
    const float c = (float)cos((double)theta);
    const float s = (float)sin((double)theta);

    srcx = 500.0f * c;
    srcy = 500.0f * s;
    const float uu = ((float)u - 47.5f) * 2.0f;
    const float vv = ((float)v - 47.5f) * 2.0f;
    const float pixx = (-500.0f * c) + uu * (-s);
    const float pixy = (-500.0f * s) + uu * c;
    const float pixz = vv;

    const float dx0 = pixx - srcx;
    const float dy0 = pixy - srcy;
    const float dz0 = pixz;
    const float nrm = sqrtf((dx0 * dx0 + dy0 * dy0) + dz0 * dz0);
    dx = dx0 / nrm;
    dy = dy0 / nrm;
    dz = dz0 / nrm;

    const float stepf = (float)1.7320508075688773;   // f32(2R/96)
    const float t0f   = (float)416.8615612366939;    // f32(DSO-R)

    // conservative AABB clip (skip-only; in-loop test is authoritative)
    const float LO = -47.51f, HI = 47.51f;
    float tlo = -1e30f, thi = 1e30f;
    {
        const float o3[3] = {srcx, srcy, 0.0f};
        const float d3[3] = {dx, dy, dz};
        bool empty = false;
        #pragma unroll
        for (int ax = 0; ax < 3; ++ax) {
            const float oo = o3[ax], dd = d3[ax];
            if (fabsf(dd) > 1e-8f) {
                const float inv = 1.0f / dd;
                const float ta = (LO - oo) * inv;
                const float tb = (HI - oo) * inv;
                tlo = fmaxf(tlo, fminf(ta, tb));
                thi = fminf(thi, fmaxf(ta, tb));
            } else if (oo < LO || oo > HI) {
                empty = true;
            }
        }
        if (empty) { tlo = 1.0f; thi = 0.0f; }
    }
    if (thi >= tlo) {
        k0 = (int)floorf((tlo - t0f) / stepf) - 2;
        k1 = (int)ceilf((thi - t0f) / stepf) + 2;
        k0 = max(k0, 0);
        k1 = min(k1, NSg - 1);
    } else {
        k0 = 1; k1 = 0;
    }
}

// ---------------- main: both batches per thread, tiled layout -------------
__global__ __launch_bounds__(256) void coneproj_tiled(
    const float2* __restrict__ q, float* __restrict__ out) {
#pragma clang fp contract(off)
    const int ridx = blockIdx.x * blockDim.x + threadIdx.x;  // (a*96+v)*96+u
    float srcx, srcy, dx, dy, dz;
    int k0, k1;
    ray_setup(ridx, srcx, srcy, dx, dy, dz, k0, k1);

    const float stepf = (float)1.7320508075688773;
    const float t0f   = (float)416.8615612366939;

    float acc0 = 0.0f, acc1 = 0.0f;
    for (int k = k0; k <= k1; ++k) {
        const float tk = t0f + ((float)k + 0.5f) * stepf;
        const float ix = (srcx + dx * tk) + 47.5f;
        const float iy = (srcy + dy * tk) + 47.5f;
        const float iz = (dz * tk) + 47.5f;
        if (ix >= 0.0f && ix <= 95.0f &&
            iy >= 0.0f && iy <= 95.0f &&
            iz >= 0.0f && iz <= 95.0f) {
            const int x0 = min((int)ix, NXg - 2);
            const int y0 = min((int)iy, NYg - 2);
            const int z0 = min((int)iz, NZg - 2);
            const float fx = ix - (float)x0;
            const float fy = iy - (float)y0;
            const float fz = iz - (float)z0;
            // tiled addressing: base + data-dependent small deltas
            const int base = tiled_idx(x0, y0, z0);
            const int dX = ((x0 & 3) < 3) ? 1 : 5;          // x0+1 step
            const int dY = ((y0 & 1) == 0) ? 4 : (TROW - 4); // y0+1 step
            const float2 q000 = q[base];
            const float2 q001 = q[base + dX];
            const float2 q010 = q[base + dY];
            const float2 q011 = q[base + dY + dX];
            const float2 q100 = q[base + PLANE];
            const float2 q101 = q[base + PLANE + dX];
            const float2 q110 = q[base + PLANE + dY];
            const float2 q111 = q[base + PLANE + dY + dX];
            // batch 0 (op-order identical to R2/R7)
            {
                const float c00 = q000.x + fx * (q001.x - q000.x);
                const float c01 = q010.x + fx * (q011.x - q010.x);
                const float c10 = q100.x + fx * (q101.x - q100.x);
                const float c11 = q110.x + fx * (q111.x - q110.x);
                const float c0  = c00 + fy * (c01 - c00);
                const float c1  = c10 + fy * (c11 - c10);
                acc0 += c0 + fz * (c1 - c0);
            }
            // batch 1
            {
                const float c00 = q000.y + fx * (q001.y - q000.y);
                const float c01 = q010.y + fx * (q011.y - q010.y);
                const float c10 = q100.y + fx * (q101.y - q100.y);
                const float c11 = q110.y + fx * (q111.y - q110.y);
                const float c0  = c00 + fy * (c01 - c00);
                const float c1  = c10 + fy * (c11 - c10);
                acc1 += c0 + fz * (c1 - c0);
            }
        }
    }
    out[ridx]         = acc0 * stepf;
    out[ridx + NRAY1] = acc1 * stepf;
}

// ---------------- fallback: direct 8-gather projector (R2) ----------------
__global__ __launch_bounds__(256) void coneproj_direct(
    const float* __restrict__ vol, float* __restrict__ out) {
#pragma clang fp contract(off)
    const int gidx = blockIdx.x * blockDim.x + threadIdx.x;  // includes b
    const int ridx = gidx % NRAY1;
    const int b    = gidx / NRAY1;
    float srcx, srcy, dx, dy, dz;
    int k0, k1;
    ray_setup(ridx, srcx, srcy, dx, dy, dz, k0, k1);

    const float stepf = (float)1.7320508075688773;
    const float t0f   = (float)416.8615612366939;

    const float* __restrict__ volb = vol + (size_t)b * NVOX;

    float acc = 0.0f;
    for (int k = k0; k <= k1; ++k) {
        const float tk = t0f + ((float)k + 0.5f) * stepf;
        const float ix = (srcx + dx * tk) + 47.5f;
        const float iy = (srcy + dy * tk) + 47.5f;
        const float iz = (dz * tk) + 47.5f;
        if (ix >= 0.0f && ix <= 95.0f &&
            iy >= 0.0f && iy <= 95.0f &&
            iz >= 0.0f && iz <= 95.0f) {
            const int x0 = min((int)ix, NXg - 2);
            const int y0 = min((int)iy, NYg - 2);
            const int z0 = min((int)iz, NZg - 2);
            const float fx = ix - (float)x0;
            const float fy = iy - (float)y0;
            const float fz = iz - (float)z0;
            const float* p = volb + ((z0 * NYg + y0) * NXg + x0);
            const float v000 = p[0];
            const float v001 = p[1];
            const float v010 = p[NXg];
            const float v011 = p[NXg + 1];
            const float v100 = p[NYg * NXg];
            const float v101 = p[NYg * NXg + 1];
            const float v110 = p[NYg * NXg + NXg];
            const float v111 = p[NYg * NXg + NXg + 1];
            const float c00 = v000 + fx * (v001 - v000);
            const float c01 = v010 + fx * (v011 - v010);
            const float c10 = v100 + fx * (v101 - v100);
            const float c11 = v110 + fx * (v111 - v110);
            const float c0  = c00 + fy * (c01 - c00);
            const float c1  = c10 + fy * (c11 - c10);
            acc += c0 + fz * (c1 - c0);
        }
    }
    out[gidx] = acc * stepf;
}

extern "C" void kernel_launch(void* const* d_in, const int* in_sizes, int n_in,
                              void* d_out, int out_size, void* d_ws, size_t ws_size,
                              hipStream_t stream) {
    const float* vol = (const float*)d_in[0];
    float* out = (float*)d_out;
    const size_t needed = (size_t)NVOX * sizeof(float2);  // ~7.08 MB
    if (ws_size >= needed) {
        float2* q = (float2*)d_ws;
        pack_tiled<<<NVOX / 256, 256, 0, stream>>>(vol, q);
        coneproj_tiled<<<NRAY1 / 256, 256, 0, stream>>>(q, out);
    } else {
        coneproj_direct<<<(NBg * NRAY1) / 256, 256, 0, stream>>>(vol, out);
    }
}

// Round 10
// 213.385 us; speedup vs baseline: 1.1170x; 1.0339x over previous
//
#include <hip/hip_runtime.h>
#include <math.h>

// Cone-beam forward projection (TIGRE Ax analogue).
// Volume: [B=2, NZ=96, NY=96, NX=96] f32, ZYX layout (x fastest).
// Output: [B=2, A=48, NV=96, NU=96] f32.
//
// R10: R7 layout (batch-interleaved float2, linear x-fast, 7.1 MB) with the
// 8 dwordx2 gathers fused into 4 global_load_dwordx4 at 8B-aligned addresses
// (x-pair is contiguous: one 16B load = b0@x0,b1@x0,b0@x1,b1@x1 for one
// (y,z) row). Discriminates cost models: if cost is ~30cy per gather
// INSTRUCTION (fits R2/R6/R7 data), this is ~2x; if per-cacheline, neutral.
// Same bytes -> same lerp inputs -> bit-identical output.
//
// CORRECTNESS-CRITICAL: reference integrand is DISCONTINUOUS at cube faces.
// Position path replicates the reference's f32 op sequence exactly:
// contract(off), per-sample src + d*t, IEEE sqrt+div, f64-rounded trig.

#define NZg 96
#define NYg 96
#define NXg 96
#define NVg 96
#define NUg 96
#define NAg 48
#define NSg 96
#define NBg 2
#define NVOX (NZg * NYg * NXg)          // 884736 voxels per batch
#define NRAY1 (NAg * NVg * NUg)         // 442368 rays per batch
#define PLANE (NYg * NXg)               // 9216 float2 elements per z-plane

typedef float v4f __attribute__((ext_vector_type(4)));  // default (16B) align

// ---------------- staging: interleave the two batches ---------------------
__global__ __launch_bounds__(256) void pack_b2(
    const float* __restrict__ vol, float2* __restrict__ q) {
    const int i = blockIdx.x * blockDim.x + threadIdx.x;  // [z][y][x]
    float2 p;
    p.x = vol[i];
    p.y = vol[i + NVOX];
    q[i] = p;
}

// ---------------- shared geometry (b-independent) -------------------------
__device__ __forceinline__ void ray_setup(
    int ridx, float& srcx, float& srcy, float& dx, float& dy, float& dz,
    int& k0, int& k1) {
#pragma clang fp contract(off)
    const int u   = ridx % NUg;
    int tmp       = ridx / NUg;
    const int v   = tmp % NVg;
    const int a   = tmp / NVg;          // < 48, uniform per block

    // theta = a * (f32(2*pi) / 48)   [jax linspace f32 semantics]
    const float dtheta = 6.2831855f / 48.0f;
    const float theta  = (float)a * dtheta;
    const float c = (float)cos((double)theta);
    const float s = (float)sin((double)theta);

    srcx = 500.0f * c;
    srcy = 500.0f * s;
    const float uu = ((float)u - 47.5f) * 2.0f;
    const float vv = ((float)v - 47.5f) * 2.0f;
    const float pixx = (-500.0f * c) + uu * (-s);
    const float pixy = (-500.0f * s) + uu * c;
    const float pixz = vv;

    const float dx0 = pixx - srcx;
    const float dy0 = pixy - srcy;
    const float dz0 = pixz;
    const float nrm = sqrtf((dx0 * dx0 + dy0 * dy0) + dz0 * dz0);
    dx = dx0 / nrm;
    dy = dy0 / nrm;
    dz = dz0 / nrm;

    const float stepf = (float)1.7320508075688773;   // f32(2R/96)
    const float t0f   = (float)416.8615612366939;    // f32(DSO-R)

    // conservative AABB clip (skip-only; in-loop test is authoritative)
    const float LO = -47.51f, HI = 47.51f;
    float tlo = -1e30f, thi = 1e30f;
    {
        const float o3[3] = {srcx, srcy, 0.0f};
        const float d3[3] = {dx, dy, dz};
        bool empty = false;
        #pragma unroll
        for (int ax = 0; ax < 3; ++ax) {
            const float oo = o3[ax], dd = d3[ax];
            if (fabsf(dd) > 1e-8f) {
                const float inv = 1.0f / dd;
                const float ta = (LO - oo) * inv;
                const float tb = (HI - oo) * inv;
                tlo = fmaxf(tlo, fminf(ta, tb));
                thi = fminf(thi, fmaxf(ta, tb));
            } else if (oo < LO || oo > HI) {
                empty = true;
            }
        }
        if (empty) { tlo = 1.0f; thi = 0.0f; }
    }
    if (thi >= tlo) {
        k0 = (int)floorf((tlo - t0f) / stepf) - 2;
        k1 = (int)ceilf((thi - t0f) / stepf) + 2;
        k0 = max(k0, 0);
        k1 = min(k1, NSg - 1);
    } else {
        k0 = 1; k1 = 0;
    }
}

// ---------------- main: both batches per thread, x4 gathers ---------------
__global__ __launch_bounds__(256) void coneproj_b2x4(
    const float2* __restrict__ q, float* __restrict__ out) {
#pragma clang fp contract(off)
    const int ridx = blockIdx.x * blockDim.x + threadIdx.x;  // (a*96+v)*96+u
    float srcx, srcy, dx, dy, dz;
    int k0, k1;
    ray_setup(ridx, srcx, srcy, dx, dy, dz, k0, k1);

    const float stepf = (float)1.7320508075688773;
    const float t0f   = (float)416.8615612366939;

    float acc0 = 0.0f, acc1 = 0.0f;
    for (int k = k0; k <= k1; ++k) {
        const float tk = t0f + ((float)k + 0.5f) * stepf;
        const float ix = (srcx + dx * tk) + 47.5f;
        const float iy = (srcy + dy * tk) + 47.5f;
        const float iz = (dz * tk) + 47.5f;
        if (ix >= 0.0f && ix <= 95.0f &&
            iy >= 0.0f && iy <= 95.0f &&
            iz >= 0.0f && iz <= 95.0f) {
            const int x0 = min((int)ix, NXg - 2);
            const int y0 = min((int)iy, NYg - 2);
            const int z0 = min((int)iz, NZg - 2);
            const float fx = ix - (float)x0;
            const float fy = iy - (float)y0;
            const float fz = iz - (float)z0;
            const int base = (z0 * NYg + y0) * NXg + x0;
            // 4 x 16B gathers at 8B-aligned addresses: each row-load gives
            // (b0@x0, b1@x0, b0@x1, b1@x1) for one (y,z) corner row.
            const v4f r00 = *(const v4f*)(q + base);                // (y0,z0)
            const v4f r01 = *(const v4f*)(q + base + NXg);          // (y1,z0)
            const v4f r10 = *(const v4f*)(q + base + PLANE);        // (y0,z1)
            const v4f r11 = *(const v4f*)(q + base + PLANE + NXg);  // (y1,z1)
            // batch 0 (op-order identical to R2/R7): .x = b0@x0, .z = b0@x1
            {
                const float c00 = r00.x + fx * (r00.z - r00.x);
                const float c01 = r01.x + fx * (r01.z - r01.x);
                const float c10 = r10.x + fx * (r10.z - r10.x);
                const float c11 = r11.x + fx * (r11.z - r11.x);
                const float c0  = c00 + fy * (c01 - c00);
                const float c1  = c10 + fy * (c11 - c10);
                acc0 += c0 + fz * (c1 - c0);
            }
            // batch 1: .y = b1@x0, .w = b1@x1
            {
                const float c00 = r00.y + fx * (r00.w - r00.y);
                const float c01 = r01.y + fx * (r01.w - r01.y);
                const float c10 = r10.y + fx * (r10.w - r10.y);
                const float c11 = r11.y + fx * (r11.w - r11.y);
                const float c0  = c00 + fy * (c01 - c00);
                const float c1  = c10 + fy * (c11 - c10);
                acc1 += c0 + fz * (c1 - c0);
            }
        }
    }
    out[ridx]         = acc0 * stepf;
    out[ridx + NRAY1] = acc1 * stepf;
}

// ---------------- fallback: direct 8-gather projector (R2) ----------------
__global__ __launch_bounds__(256) void coneproj_direct(
    const float* __restrict__ vol, float* __restrict__ out) {
#pragma clang fp contract(off)
    const int gidx = blockIdx.x * blockDim.x + threadIdx.x;  // includes b
    const int ridx = gidx % NRAY1;
    const int b    = gidx / NRAY1;
    float srcx, srcy, dx, dy, dz;
    int k0, k1;
    ray_setup(ridx, srcx, srcy, dx, dy, dz, k0, k1);

    const float stepf = (float)1.7320508075688773;
    const float t0f   = (float)416.8615612366939;

    const float* __restrict__ volb = vol + (size_t)b * NVOX;

    float acc = 0.0f;
    for (int k = k0; k <= k1; ++k) {
        const float tk = t0f + ((float)k + 0.5f) * stepf;
        const float ix = (srcx + dx * tk) + 47.5f;
        const float iy = (srcy + dy * tk) + 47.5f;
        const float iz = (dz * tk) + 47.5f;
        if (ix >= 0.0f && ix <= 95.0f &&
            iy >= 0.0f && iy <= 95.0f &&
            iz >= 0.0f && iz <= 95.0f) {
            const int x0 = min((int)ix, NXg - 2);
            const int y0 = min((int)iy, NYg - 2);
            const int z0 = min((int)iz, NZg - 2);
            const float fx = ix - (float)x0;
            const float fy = iy - (float)y0;
            const float fz = iz - (float)z0;
            const float* p = volb + ((z0 * NYg + y0) * NXg + x0);
            const float v000 = p[0];
            const float v001 = p[1];
            const float v010 = p[NXg];
            const float v011 = p[NXg + 1];
            const float v100 = p[NYg * NXg];
            const float v101 = p[NYg * NXg + 1];
            const float v110 = p[NYg * NXg + NXg];
            const float v111 = p[NYg * NXg + NXg + 1];
            const float c00 = v000 + fx * (v001 - v000);
            const float c01 = v010 + fx * (v011 - v010);
            const float c10 = v100 + fx * (v101 - v100);
            const float c11 = v110 + fx * (v111 - v110);
            const float c0  = c00 + fy * (c01 - c00);
            const float c1  = c10 + fy * (c11 - c10);
            acc += c0 + fz * (c1 - c0);
        }
    }
    out[gidx] = acc * stepf;
}

extern "C" void kernel_launch(void* const* d_in, const int* in_sizes, int n_in,
                              void* d_out, int out_size, void* d_ws, size_t ws_size,
                              hipStream_t stream) {
    const float* vol = (const float*)d_in[0];
    float* out = (float*)d_out;
    const size_t needed = (size_t)NVOX * sizeof(float2);  // ~7.08 MB
    if (ws_size >= needed) {
        float2* q = (float2*)d_ws;
        pack_b2<<<NVOX / 256, 256, 0, stream>>>(vol, q);
        coneproj_b2x4<<<NRAY1 / 256, 256, 0, stream>>>(q, out);
    } else {
        coneproj_direct<<<(NBg * NRAY1) / 256, 256, 0, stream>>>(vol, out);
    }
}